// Round 12
// baseline (1851.035 us; speedup 1.0000x reference)
//
#include <hip/hip_runtime.h>
#include <hip/hip_bf16.h>

#define N_NODES 100000
#define N_EDGES 1600000

typedef __attribute__((ext_vector_type(4))) float f32x4;
typedef __attribute__((ext_vector_type(8))) short bf16x8;

__device__ __forceinline__ unsigned short f2bf(float v) {
    return __builtin_bit_cast(unsigned short, __float2bfloat16(v));
}
__device__ __forceinline__ float bf2f(unsigned short h) {
    return __uint_as_float(((unsigned)h) << 16);
}

// ---------------- aux kernels ----------------------------------------------
__global__ void zero_kernel(float* p, int n) {
    int i = blockIdx.x * blockDim.x + threadIdx.x;
    int stride = gridDim.x * blockDim.x;
    for (; i < n; i += stride) p[i] = 0.f;
}

// Fused: wbuf = exp(dist); s[dst] += exp; hagg1[dst,:] += exp * h_enc[src,:]
// (softmax division deferred to norm_kernel: sum(e_i/s * h) == (sum e_i*h)/s)
__global__ void exp_agg_kernel(const float* __restrict__ dist,
                               const int* __restrict__ src, const int* __restrict__ dst,
                               const float* __restrict__ h,
                               float* __restrict__ s, float* __restrict__ wbuf,
                               float* __restrict__ hagg, int E) {
    int e = blockIdx.x * blockDim.x + threadIdx.x;
    if (e >= E) return;
    float v = expf(dist[e]);
    wbuf[e] = v;
    int d = dst[e], sr = src[e];
    atomicAdd(s + d, v);
    float4 A = *(const float4*)(h + sr * 8);
    float4 B = *(const float4*)(h + sr * 8 + 4);
    float* o = hagg + d * 8;
    atomicAdd(o + 0, v * A.x); atomicAdd(o + 1, v * A.y);
    atomicAdd(o + 2, v * A.z); atomicAdd(o + 3, v * A.w);
    atomicAdd(o + 4, v * B.x); atomicAdd(o + 5, v * B.y);
    atomicAdd(o + 6, v * B.z); atomicAdd(o + 7, v * B.w);
}

// Second weighted aggregation, thread-per-edge, raw exp weights (divide later)
__global__ void agg2_kernel(const float* __restrict__ wbuf, const float* __restrict__ h,
                            const int* __restrict__ src, const int* __restrict__ dst,
                            float* __restrict__ out, int E) {
    int e = blockIdx.x * blockDim.x + threadIdx.x;
    if (e >= E) return;
    float v = wbuf[e];
    int d = dst[e], sr = src[e];
    float4 A = *(const float4*)(h + sr * 8);
    float4 B = *(const float4*)(h + sr * 8 + 4);
    float* o = out + d * 8;
    atomicAdd(o + 0, v * A.x); atomicAdd(o + 1, v * A.y);
    atomicAdd(o + 2, v * A.z); atomicAdd(o + 3, v * A.w);
    atomicAdd(o + 4, v * B.x); atomicAdd(o + 5, v * B.y);
    atomicAdd(o + 6, v * B.z); atomicAdd(o + 7, v * B.w);
}

// hagg1 /= s (in place); rs = 1/s cached for the decoder's hagg2 normalize
__global__ void norm_kernel(float* __restrict__ hagg, const float* __restrict__ s,
                            float* __restrict__ rs, int N) {
    int d = blockIdx.x * blockDim.x + threadIdx.x;
    if (d >= N) return;
    float r = 1.f / s[d];
    rs[d] = r;
    float4 a = *(const float4*)(hagg + d * 8);
    float4 b = *(const float4*)(hagg + d * 8 + 4);
    a.x *= r; a.y *= r; a.z *= r; a.w *= r;
    b.x *= r; b.y *= r; b.z *= r; b.w *= r;
    *(float4*)(hagg + d * 8) = a;
    *(float4*)(hagg + d * 8 + 4) = b;
}

// ---------------- node-MLP weight packing (fp32 path) ----------------------
struct PackArgs { const float *w1, *b1, *w2; float* out; int din, stride; };

__global__ void pack_kernel(PackArgs a0, PackArgs a1, PackArgs a2) {
    PackArgs a = (blockIdx.x == 0) ? a0 : (blockIdx.x == 1) ? a1 : a2;
    int k = threadIdx.x;  // 64 threads
    float* row = a.out + k * a.stride;
    for (int j = 0; j < 64; ++j) row[j] = a.w2[k * 64 + j];
    for (int j = 0; j < a.din; ++j) row[64 + j] = a.w1[j * 64 + k];
    row[64 + a.din] = a.b1[k];
}

// edge weights -> split-bf16 (R10-proven layouts).
// w1: [ch][j(32-padded)], j = x index (0=he, 1..8 hsrc, 9..16 hdst).
// w2: kappa'-order: outch=16mt+row, ch = ks*32 + 16*(i>>2) + 4g + (i&3).
__global__ void pack_edge_kernel(const float* __restrict__ w1, const float* __restrict__ w2,
                                 unsigned short* __restrict__ w1hi, unsigned short* __restrict__ w1lo,
                                 unsigned short* __restrict__ w2hi, unsigned short* __restrict__ w2lo) {
    int c = threadIdx.x;  // 64 threads; c = ch (w1) / outch (w2)
    for (int j = 0; j < 32; ++j) {
        float v = (j < 17) ? w1[j * 64 + c] : 0.f;
        unsigned short hi = f2bf(v);
        w1hi[c * 32 + j] = hi;
        w1lo[c * 32 + j] = f2bf(v - bf2f(hi));
    }
    int mt = c >> 4, row = c & 15;
    for (int ch = 0; ch < 64; ++ch) {
        int ks = ch >> 5, r5 = ch & 31;
        int i = ((r5 >> 4) << 2) | (r5 & 3);
        int g = (r5 >> 2) & 3;
        int dstIdx = (((mt * 2 + ks) * 16 + row) * 4 + g) * 8 + i;
        float v = w2[ch * 64 + c];
        unsigned short hi = f2bf(v);
        w2hi[dstIdx] = hi;
        w2lo[dstIdx] = f2bf(v - bf2f(hi));
    }
}

// ---------------- fp32 node MLP (R6 proven): DIN -> 64 -> 64 -> DOUT -------
template <int DIN, int DOUT, int STRIDE>
__device__ __forceinline__ void mlp_fused(
    const float* __restrict__ x, const float* __restrict__ wp,
    const float* __restrict__ b2,
    const float* __restrict__ w3, const float* __restrict__ b3,
    float* __restrict__ out) {
    float h2[64];
#pragma unroll
    for (int j = 0; j < 64; ++j) h2[j] = b2[j];
    for (int k = 0; k < 64; ++k) {
        const float* row = wp + k * STRIDE;
        float a = row[64 + DIN];
#pragma unroll
        for (int j = 0; j < DIN; ++j) a = fmaf(x[j], row[64 + j], a);
        a = fmaxf(a, 0.f);
#pragma unroll
        for (int j = 0; j < 64; ++j) h2[j] = fmaf(a, row[j], h2[j]);
    }
    float acc[DOUT];
#pragma unroll
    for (int o = 0; o < DOUT; ++o) acc[o] = b3[o];
#pragma unroll
    for (int j = 0; j < 64; ++j) {
        float r = fmaxf(h2[j], 0.f);
#pragma unroll
        for (int o = 0; o < DOUT; ++o) acc[o] = fmaf(r, w3[j * DOUT + o], acc[o]);
    }
#pragma unroll
    for (int o = 0; o < DOUT; ++o) out[o] = fmaxf(acc[o], 0.f);
}

// rs: optional per-item input scale (decoder: hagg2 * (1/s)); nullptr = 1.0
template <int CA, int CB, int DOUT, int STRIDE>
__global__ __launch_bounds__(256, 3) void node_mlp_kernel(
    const float* __restrict__ xa, const float* __restrict__ xb,
    const float* __restrict__ rs,
    const float* __restrict__ wp, const float* __restrict__ b2,
    const float* __restrict__ w3, const float* __restrict__ b3,
    float* __restrict__ out, int n) {
    constexpr int DIN = CA + CB;
    int i = blockIdx.x * 256 + threadIdx.x;
    if (i >= n) return;
    float scale = rs ? rs[i] : 1.f;
    float x[DIN];
#pragma unroll
    for (int k = 0; k < CA; ++k) x[k] = xa[i * CA + k] * scale;
    if (CB == 8) {
        float4 v0 = *(const float4*)(xb + i * 8);
        float4 v1 = *(const float4*)(xb + i * 8 + 4);
        x[CA + 0] = v0.x; x[CA + 1] = v0.y; x[CA + 2] = v0.z; x[CA + 3] = v0.w;
        x[CA + 4] = v1.x; x[CA + 5] = v1.y; x[CA + 6] = v1.z; x[CA + 7] = v1.w;
    }
    float o[DOUT];
    mlp_fused<DIN, DOUT, STRIDE>(x, wp, b2, w3, b3, o);
#pragma unroll
    for (int k = 0; k < DOUT; ++k) out[i * DOUT + k] = o[k];
}

// ---------------- split-bf16 MFMA edge MLP (R10-proven): 17->64->64->1 -----
// 2 waves/block, 64 edges/wave. Layer-1 X staged in LDS; layer-2 consumes
// layer-1 accumulators from registers (kappa'-packed w2). Split product:
// hi*hi + hi*lo + lo*hi.
__global__ __launch_bounds__(128, 2) void edge_mlp_mfma_kernel(
    const float* __restrict__ he_in, const float* __restrict__ h,
    const int* __restrict__ src, const int* __restrict__ dst,
    const unsigned short* __restrict__ w1hi, const unsigned short* __restrict__ w1lo,
    const unsigned short* __restrict__ w2hi, const unsigned short* __restrict__ w2lo,
    const float* __restrict__ b1, const float* __restrict__ b2,
    const float* __restrict__ w3, const float* __restrict__ b3,
    float* __restrict__ he_out, float* __restrict__ agg) {
    __shared__ __align__(16) unsigned char smem[2 * 10240];
    const int lane = threadIdx.x & 63, wv = threadIdx.x >> 6;
    unsigned char* W = smem + wv * 10240;
    const int ebase = (blockIdx.x * 2 + wv) * 64;

    // ---- phase 1: gather x[17], split, stage to LDS (hi @0, lo @5120) ----
    {
        int e = ebase + lane;
        float x[32];
        x[0] = he_in[e];
        int sr = src[e], dd = dst[e];
        float4 a0 = *(const float4*)(h + sr * 8);
        float4 a1 = *(const float4*)(h + sr * 8 + 4);
        float4 d0 = *(const float4*)(h + dd * 8);
        float4 d1 = *(const float4*)(h + dd * 8 + 4);
        x[1] = a0.x;  x[2] = a0.y;  x[3] = a0.z;  x[4] = a0.w;
        x[5] = a1.x;  x[6] = a1.y;  x[7] = a1.z;  x[8] = a1.w;
        x[9] = d0.x;  x[10] = d0.y; x[11] = d0.z; x[12] = d0.w;
        x[13] = d1.x; x[14] = d1.y; x[15] = d1.z; x[16] = d1.w;
#pragma unroll
        for (int j = 17; j < 32; ++j) x[j] = 0.f;
        unsigned uh[16], ul[16];
#pragma unroll
        for (int jj = 0; jj < 16; ++jj) {
            unsigned short h0 = f2bf(x[2 * jj]);
            unsigned short h1v = f2bf(x[2 * jj + 1]);
            unsigned short l0 = f2bf(x[2 * jj] - bf2f(h0));
            unsigned short l1 = f2bf(x[2 * jj + 1] - bf2f(h1v));
            uh[jj] = (unsigned)h0 | ((unsigned)h1v << 16);
            ul[jj] = (unsigned)l0 | ((unsigned)l1 << 16);
        }
        uint4* ph = (uint4*)(W + lane * 80);
        uint4* pl = (uint4*)(W + 5120 + lane * 80);
#pragma unroll
        for (int q = 0; q < 4; ++q) {
            ph[q] = make_uint4(uh[4 * q], uh[4 * q + 1], uh[4 * q + 2], uh[4 * q + 3]);
            pl[q] = make_uint4(ul[4 * q], ul[4 * q + 1], ul[4 * q + 2], ul[4 * q + 3]);
        }
    }
    __syncthreads();
    const int row = lane & 15, g = lane >> 4;

    // ---- layer 1: D1[ch][edge] ----
    bf16x8 wa_h[4], wa_l[4];
#pragma unroll
    for (int mt = 0; mt < 4; ++mt) {
        wa_h[mt] = *(const bf16x8*)(w1hi + (16 * mt + row) * 32 + g * 8);
        wa_l[mt] = *(const bf16x8*)(w1lo + (16 * mt + row) * 32 + g * 8);
    }
    bf16x8 xb_h[4], xb_l[4];
#pragma unroll
    for (int nt = 0; nt < 4; ++nt) {
        xb_h[nt] = *(const bf16x8*)(W + (16 * nt + row) * 80 + g * 16);
        xb_l[nt] = *(const bf16x8*)(W + 5120 + (16 * nt + row) * 80 + g * 16);
    }
    f32x4 c1[4][4];
#pragma unroll
    for (int mt = 0; mt < 4; ++mt)
#pragma unroll
        for (int nt = 0; nt < 4; ++nt) {
            f32x4 c = {0.f, 0.f, 0.f, 0.f};
            c = __builtin_amdgcn_mfma_f32_16x16x32_bf16(wa_h[mt], xb_h[nt], c, 0, 0, 0);
            c = __builtin_amdgcn_mfma_f32_16x16x32_bf16(wa_h[mt], xb_l[nt], c, 0, 0, 0);
            c = __builtin_amdgcn_mfma_f32_16x16x32_bf16(wa_l[mt], xb_h[nt], c, 0, 0, 0);
            c1[mt][nt] = c;
        }

    // ---- bias+relu+split IN REGISTERS -> layer-2 B fragments (kappa') ----
    float4 b1v[4];
#pragma unroll
    for (int mt = 0; mt < 4; ++mt) b1v[mt] = *(const float4*)(b1 + 16 * mt + g * 4);
    bf16x8 pb_h[4][2], pb_l[4][2];
#pragma unroll
    for (int nt = 0; nt < 4; ++nt)
#pragma unroll
        for (int ks = 0; ks < 2; ++ks) {
            float v0 = fmaxf(c1[2 * ks][nt].x + b1v[2 * ks].x, 0.f);
            float v1 = fmaxf(c1[2 * ks][nt].y + b1v[2 * ks].y, 0.f);
            float v2 = fmaxf(c1[2 * ks][nt].z + b1v[2 * ks].z, 0.f);
            float v3 = fmaxf(c1[2 * ks][nt].w + b1v[2 * ks].w, 0.f);
            float v4 = fmaxf(c1[2 * ks + 1][nt].x + b1v[2 * ks + 1].x, 0.f);
            float v5 = fmaxf(c1[2 * ks + 1][nt].y + b1v[2 * ks + 1].y, 0.f);
            float v6 = fmaxf(c1[2 * ks + 1][nt].z + b1v[2 * ks + 1].z, 0.f);
            float v7 = fmaxf(c1[2 * ks + 1][nt].w + b1v[2 * ks + 1].w, 0.f);
            unsigned short h0 = f2bf(v0), h1v = f2bf(v1), h2v = f2bf(v2), h3 = f2bf(v3);
            unsigned short h4 = f2bf(v4), h5 = f2bf(v5), h6 = f2bf(v6), h7 = f2bf(v7);
            bf16x8 ph, pl;
            ph[0] = h0; ph[1] = h1v; ph[2] = h2v; ph[3] = h3;
            ph[4] = h4; ph[5] = h5;  ph[6] = h6;  ph[7] = h7;
            pl[0] = f2bf(v0 - bf2f(h0)); pl[1] = f2bf(v1 - bf2f(h1v));
            pl[2] = f2bf(v2 - bf2f(h2v)); pl[3] = f2bf(v3 - bf2f(h3));
            pl[4] = f2bf(v4 - bf2f(h4)); pl[5] = f2bf(v5 - bf2f(h5));
            pl[6] = f2bf(v6 - bf2f(h6)); pl[7] = f2bf(v7 - bf2f(h7));
            pb_h[nt][ks] = ph;
            pb_l[nt][ks] = pl;
        }

    // ---- layer 2: D2[outch][edge], A = w2 (kappa'-packed), B = pb ----
    f32x4 c2[4][4];
#pragma unroll
    for (int mt = 0; mt < 4; ++mt)
#pragma unroll
        for (int nt = 0; nt < 4; ++nt) c2[mt][nt] = (f32x4){0.f, 0.f, 0.f, 0.f};
#pragma unroll
    for (int mt = 0; mt < 4; ++mt) {
        bf16x8 w2a_h[2], w2a_l[2];
#pragma unroll
        for (int ks = 0; ks < 2; ++ks) {
            int off = (((mt * 2 + ks) * 16 + row) * 4 + g) * 8;
            w2a_h[ks] = *(const bf16x8*)(w2hi + off);
            w2a_l[ks] = *(const bf16x8*)(w2lo + off);
        }
#pragma unroll
        for (int nt = 0; nt < 4; ++nt)
#pragma unroll
            for (int ks = 0; ks < 2; ++ks) {
                c2[mt][nt] = __builtin_amdgcn_mfma_f32_16x16x32_bf16(w2a_h[ks], pb_h[nt][ks], c2[mt][nt], 0, 0, 0);
                c2[mt][nt] = __builtin_amdgcn_mfma_f32_16x16x32_bf16(w2a_h[ks], pb_l[nt][ks], c2[mt][nt], 0, 0, 0);
                c2[mt][nt] = __builtin_amdgcn_mfma_f32_16x16x32_bf16(w2a_l[ks], pb_h[nt][ks], c2[mt][nt], 0, 0, 0);
            }
    }

    // ---- layer 3 epilogue: out = relu(b3 + sum_ch relu(h2)*w3) ----
    float4 b2v[4], w3v[4];
#pragma unroll
    for (int mt = 0; mt < 4; ++mt) {
        b2v[mt] = *(const float4*)(b2 + 16 * mt + g * 4);
        w3v[mt] = *(const float4*)(w3 + 16 * mt + g * 4);
    }
    float b3s = b3[0];
    float pacc[4];
#pragma unroll
    for (int nt = 0; nt < 4; ++nt) {
        float p = 0.f;
#pragma unroll
        for (int mt = 0; mt < 4; ++mt) {
            p = fmaf(fmaxf(c2[mt][nt].x + b2v[mt].x, 0.f), w3v[mt].x, p);
            p = fmaf(fmaxf(c2[mt][nt].y + b2v[mt].y, 0.f), w3v[mt].y, p);
            p = fmaf(fmaxf(c2[mt][nt].z + b2v[mt].z, 0.f), w3v[mt].z, p);
            p = fmaf(fmaxf(c2[mt][nt].w + b2v[mt].w, 0.f), w3v[mt].w, p);
        }
        p += __shfl_xor(p, 16);
        p += __shfl_xor(p, 32);
        pacc[nt] = p;
    }
    if (lane < 16) {
#pragma unroll
        for (int nt = 0; nt < 4; ++nt) {
            int e2 = ebase + 16 * nt + lane;
            float o = fmaxf(pacc[nt] + b3s, 0.f);
            he_out[e2] = o;
            atomicAdd(agg + dst[e2], o);
        }
    }
}

extern "C" void kernel_launch(void* const* d_in, const int* in_sizes, int n_in,
                              void* d_out, int out_size, void* d_ws, size_t ws_size,
                              hipStream_t stream) {
    const int N = N_NODES, E = N_EDGES;
    const float* node_feat = (const float*)d_in[0];
    const float* edge_feat = (const float*)d_in[1];
    const float* edge_dist = (const float*)d_in[2];
    const int* src = (const int*)d_in[3];
    const int* dst = (const int*)d_in[4];
    const float* w_enc1 = (const float*)d_in[5];  const float* b_enc1 = (const float*)d_in[6];
    const float* w_enc2 = (const float*)d_in[7];  const float* b_enc2 = (const float*)d_in[8];
    const float* w_enc3 = (const float*)d_in[9];  const float* b_enc3 = (const float*)d_in[10];
    const float* w_dec1 = (const float*)d_in[11]; const float* b_dec1 = (const float*)d_in[12];
    const float* w_dec2 = (const float*)d_in[13]; const float* b_dec2 = (const float*)d_in[14];
    const float* w_dec3 = (const float*)d_in[15]; const float* b_dec3 = (const float*)d_in[16];
    const float* w_nod1 = (const float*)d_in[17]; const float* b_nod1 = (const float*)d_in[18];
    const float* w_nod2 = (const float*)d_in[19]; const float* b_nod2 = (const float*)d_in[20];
    const float* w_nod3 = (const float*)d_in[21]; const float* b_nod3 = (const float*)d_in[22];
    const float* w_edg1 = (const float*)d_in[23]; const float* b_edg1 = (const float*)d_in[24];
    const float* w_edg2 = (const float*)d_in[25]; const float* b_edg2 = (const float*)d_in[26];
    const float* w_edg3 = (const float*)d_in[27]; const float* b_edg3 = (const float*)d_in[28];

    float* ws = (float*)d_ws;
    float* s      = ws;            // N
    float* hagg1  = ws + N;        // 8N
    float* agg1   = ws + 9 * N;    // N
    float* agg2   = ws + 10 * N;   // N
    float* hagg2  = ws + 11 * N;   // 8N   (zero range = 19N)
    float* rs     = ws + 19 * N;   // N (fully written by norm_kernel)
    float* h_enc  = ws + 20 * N;
    float* h_r1   = ws + 28 * N;
    float* h_r2   = ws + 36 * N;
    float* wbuf   = ws + 44 * N;
    float* he1    = wbuf + E;
    float* he2    = he1 + E;
    float* pk_enc = he2 + E;            // 64*80
    float* pk_nod = pk_enc + 64 * 80;   // 64*80
    float* pk_dec = pk_nod + 64 * 80;   // 64*80
    unsigned short* w1hi = (unsigned short*)(pk_dec + 64 * 80);
    unsigned short* w1lo = w1hi + 64 * 32;
    unsigned short* w2hi = w1lo + 64 * 32;
    unsigned short* w2lo = w2hi + 64 * 64;

    // pack weights (runs every call; inputs restored by harness)
    PackArgs pa0{w_enc1, b_enc1, w_enc2, pk_enc, 3, 80};
    PackArgs pa1{w_nod1, b_nod1, w_nod2, pk_nod, 9, 80};
    PackArgs pa2{w_dec1, b_dec1, w_dec2, pk_dec, 8, 80};
    pack_kernel<<<3, 64, 0, stream>>>(pa0, pa1, pa2);
    pack_edge_kernel<<<1, 64, 0, stream>>>(w_edg1, w_edg2, w1hi, w1lo, w2hi, w2lo);

    // zero accumulators (s, hagg1, agg1, agg2, hagg2)
    zero_kernel<<<2048, 256, 0, stream>>>(ws, 19 * N);
    // encoder
    node_mlp_kernel<3, 0, 8, 80><<<(N + 255) / 256, 256, 0, stream>>>(node_feat, nullptr,
        nullptr, pk_enc, b_enc2, w_enc3, b_enc3, h_enc, N);
    // fused softmax-numerator + first aggregation (raw exp weights)
    exp_agg_kernel<<<(E + 255) / 256, 256, 0, stream>>>(edge_dist, src, dst, h_enc,
        s, wbuf, hagg1, E);
    // normalize hagg1 by s; cache rs = 1/s for decoder
    norm_kernel<<<(N + 255) / 256, 256, 0, stream>>>(hagg1, s, rs, N);
    // round 1  (E = 128*12500 exactly)
    edge_mlp_mfma_kernel<<<E / 128, 128, 0, stream>>>(edge_feat, hagg1, src, dst,
        w1hi, w1lo, w2hi, w2lo, b_edg1, b_edg2, w_edg3, b_edg3, he1, agg1);
    node_mlp_kernel<1, 8, 8, 80><<<(N + 255) / 256, 256, 0, stream>>>(agg1, hagg1,
        nullptr, pk_nod, b_nod2, w_nod3, b_nod3, h_r1, N);
    // round 2
    edge_mlp_mfma_kernel<<<E / 128, 128, 0, stream>>>(he1, h_r1, src, dst,
        w1hi, w1lo, w2hi, w2lo, b_edg1, b_edg2, w_edg3, b_edg3, he2, agg2);
    node_mlp_kernel<1, 8, 8, 80><<<(N + 255) / 256, 256, 0, stream>>>(agg2, h_r1,
        nullptr, pk_nod, b_nod2, w_nod3, b_nod3, h_r2, N);
    // second weighted aggregation (raw exp; decoder divides by s via rs)
    agg2_kernel<<<(E + 255) / 256, 256, 0, stream>>>(wbuf, h_r2, src, dst, hagg2, E);
    // decoder -> output (x = hagg2 * rs)
    node_mlp_kernel<8, 0, 1, 80><<<(N + 255) / 256, 256, 0, stream>>>(hagg2, nullptr,
        rs, pk_dec, b_dec2, w_dec3, b_dec3, (float*)d_out, N);
}

// Round 13
// 721.360 us; speedup vs baseline: 2.5660x; 2.5660x over previous
//
#include <hip/hip_runtime.h>
#include <hip/hip_bf16.h>

#define N_NODES 100000
#define N_EDGES 1600000

typedef __attribute__((ext_vector_type(4))) float f32x4;
typedef __attribute__((ext_vector_type(8))) short bf16x8;

__device__ __forceinline__ unsigned short f2bf(float v) {
    return __builtin_bit_cast(unsigned short, __float2bfloat16(v));
}
__device__ __forceinline__ float bf2f(unsigned short h) {
    return __uint_as_float(((unsigned)h) << 16);
}

// ---------------- aux kernels ----------------------------------------------
__global__ void zero_kernel(float* p, int n) {
    int i = blockIdx.x * blockDim.x + threadIdx.x;
    int stride = gridDim.x * blockDim.x;
    for (; i < n; i += stride) p[i] = 0.f;
}

// Fused first aggregation, E*8 threads (COALESCED scatter: an edge's 8
// channel-atomics sit in 8 adjacent lanes of one instruction).
// Deferred softmax division: hagg accumulates raw exp weights; norm_kernel
// divides by s afterward. Lane c==0 also writes wbuf and the s atomic.
__global__ void exp_agg_kernel(const float* __restrict__ dist,
                               const int* __restrict__ src, const int* __restrict__ dst,
                               const float* __restrict__ h,
                               float* __restrict__ s, float* __restrict__ wbuf,
                               float* __restrict__ hagg, int E) {
    int t = blockIdx.x * blockDim.x + threadIdx.x;
    if (t >= E * 8) return;
    int e = t >> 3, c = t & 7;
    float v = expf(dist[e]);
    int d = dst[e];
    if (c == 0) {
        wbuf[e] = v;
        atomicAdd(s + d, v);
    }
    atomicAdd(hagg + d * 8 + c, v * h[src[e] * 8 + c]);
}

// Second weighted aggregation, E*8 threads, raw exp weights (divide in decoder)
__global__ void agg2_kernel(const float* __restrict__ wbuf, const float* __restrict__ h,
                            const int* __restrict__ src, const int* __restrict__ dst,
                            float* __restrict__ out, int E) {
    int t = blockIdx.x * blockDim.x + threadIdx.x;
    if (t >= E * 8) return;
    int e = t >> 3, c = t & 7;
    float v = wbuf[e];
    atomicAdd(out + dst[e] * 8 + c, v * h[src[e] * 8 + c]);
}

// hagg1 /= s (in place); rs = 1/s cached for the decoder's hagg2 normalize
__global__ void norm_kernel(float* __restrict__ hagg, const float* __restrict__ s,
                            float* __restrict__ rs, int N) {
    int d = blockIdx.x * blockDim.x + threadIdx.x;
    if (d >= N) return;
    float r = 1.f / s[d];
    rs[d] = r;
    float4 a = *(const float4*)(hagg + d * 8);
    float4 b = *(const float4*)(hagg + d * 8 + 4);
    a.x *= r; a.y *= r; a.z *= r; a.w *= r;
    b.x *= r; b.y *= r; b.z *= r; b.w *= r;
    *(float4*)(hagg + d * 8) = a;
    *(float4*)(hagg + d * 8 + 4) = b;
}

// ---------------- node-MLP weight packing (fp32 path) ----------------------
struct PackArgs { const float *w1, *b1, *w2; float* out; int din, stride; };

__global__ void pack_kernel(PackArgs a0, PackArgs a1, PackArgs a2) {
    PackArgs a = (blockIdx.x == 0) ? a0 : (blockIdx.x == 1) ? a1 : a2;
    int k = threadIdx.x;  // 64 threads
    float* row = a.out + k * a.stride;
    for (int j = 0; j < 64; ++j) row[j] = a.w2[k * 64 + j];
    for (int j = 0; j < a.din; ++j) row[64 + j] = a.w1[j * 64 + k];
    row[64 + a.din] = a.b1[k];
}

// edge weights -> split-bf16 (R10-proven layouts).
// w1: [ch][j(32-padded)], j = x index (0=he, 1..8 hsrc, 9..16 hdst).
// w2: kappa'-order: outch=16mt+row, ch = ks*32 + 16*(i>>2) + 4g + (i&3).
__global__ void pack_edge_kernel(const float* __restrict__ w1, const float* __restrict__ w2,
                                 unsigned short* __restrict__ w1hi, unsigned short* __restrict__ w1lo,
                                 unsigned short* __restrict__ w2hi, unsigned short* __restrict__ w2lo) {
    int c = threadIdx.x;  // 64 threads; c = ch (w1) / outch (w2)
    for (int j = 0; j < 32; ++j) {
        float v = (j < 17) ? w1[j * 64 + c] : 0.f;
        unsigned short hi = f2bf(v);
        w1hi[c * 32 + j] = hi;
        w1lo[c * 32 + j] = f2bf(v - bf2f(hi));
    }
    int mt = c >> 4, row = c & 15;
    for (int ch = 0; ch < 64; ++ch) {
        int ks = ch >> 5, r5 = ch & 31;
        int i = ((r5 >> 4) << 2) | (r5 & 3);
        int g = (r5 >> 2) & 3;
        int dstIdx = (((mt * 2 + ks) * 16 + row) * 4 + g) * 8 + i;
        float v = w2[ch * 64 + c];
        unsigned short hi = f2bf(v);
        w2hi[dstIdx] = hi;
        w2lo[dstIdx] = f2bf(v - bf2f(hi));
    }
}

// ---------------- fp32 node MLP (R6 proven): DIN -> 64 -> 64 -> DOUT -------
template <int DIN, int DOUT, int STRIDE>
__device__ __forceinline__ void mlp_fused(
    const float* __restrict__ x, const float* __restrict__ wp,
    const float* __restrict__ b2,
    const float* __restrict__ w3, const float* __restrict__ b3,
    float* __restrict__ out) {
    float h2[64];
#pragma unroll
    for (int j = 0; j < 64; ++j) h2[j] = b2[j];
    for (int k = 0; k < 64; ++k) {
        const float* row = wp + k * STRIDE;
        float a = row[64 + DIN];
#pragma unroll
        for (int j = 0; j < DIN; ++j) a = fmaf(x[j], row[64 + j], a);
        a = fmaxf(a, 0.f);
#pragma unroll
        for (int j = 0; j < 64; ++j) h2[j] = fmaf(a, row[j], h2[j]);
    }
    float acc[DOUT];
#pragma unroll
    for (int o = 0; o < DOUT; ++o) acc[o] = b3[o];
#pragma unroll
    for (int j = 0; j < 64; ++j) {
        float r = fmaxf(h2[j], 0.f);
#pragma unroll
        for (int o = 0; o < DOUT; ++o) acc[o] = fmaf(r, w3[j * DOUT + o], acc[o]);
    }
#pragma unroll
    for (int o = 0; o < DOUT; ++o) out[o] = fmaxf(acc[o], 0.f);
}

// rs: optional per-item input scale (decoder: hagg2 * (1/s)); nullptr = 1.0
template <int CA, int CB, int DOUT, int STRIDE>
__global__ __launch_bounds__(256, 3) void node_mlp_kernel(
    const float* __restrict__ xa, const float* __restrict__ xb,
    const float* __restrict__ rs,
    const float* __restrict__ wp, const float* __restrict__ b2,
    const float* __restrict__ w3, const float* __restrict__ b3,
    float* __restrict__ out, int n) {
    constexpr int DIN = CA + CB;
    int i = blockIdx.x * 256 + threadIdx.x;
    if (i >= n) return;
    float scale = rs ? rs[i] : 1.f;
    float x[DIN];
#pragma unroll
    for (int k = 0; k < CA; ++k) x[k] = xa[i * CA + k] * scale;
    if (CB == 8) {
        float4 v0 = *(const float4*)(xb + i * 8);
        float4 v1 = *(const float4*)(xb + i * 8 + 4);
        x[CA + 0] = v0.x; x[CA + 1] = v0.y; x[CA + 2] = v0.z; x[CA + 3] = v0.w;
        x[CA + 4] = v1.x; x[CA + 5] = v1.y; x[CA + 6] = v1.z; x[CA + 7] = v1.w;
    }
    float o[DOUT];
    mlp_fused<DIN, DOUT, STRIDE>(x, wp, b2, w3, b3, o);
#pragma unroll
    for (int k = 0; k < DOUT; ++k) out[i * DOUT + k] = o[k];
}

// ---------------- split-bf16 MFMA edge MLP (R10-proven): 17->64->64->1 -----
// 2 waves/block, 64 edges/wave. Layer-1 X staged in LDS; layer-2 consumes
// layer-1 accumulators from registers (kappa'-packed w2). Split product:
// hi*hi + hi*lo + lo*hi.
__global__ __launch_bounds__(128, 2) void edge_mlp_mfma_kernel(
    const float* __restrict__ he_in, const float* __restrict__ h,
    const int* __restrict__ src, const int* __restrict__ dst,
    const unsigned short* __restrict__ w1hi, const unsigned short* __restrict__ w1lo,
    const unsigned short* __restrict__ w2hi, const unsigned short* __restrict__ w2lo,
    const float* __restrict__ b1, const float* __restrict__ b2,
    const float* __restrict__ w3, const float* __restrict__ b3,
    float* __restrict__ he_out, float* __restrict__ agg) {
    __shared__ __align__(16) unsigned char smem[2 * 10240];
    const int lane = threadIdx.x & 63, wv = threadIdx.x >> 6;
    unsigned char* W = smem + wv * 10240;
    const int ebase = (blockIdx.x * 2 + wv) * 64;

    // ---- phase 1: gather x[17], split, stage to LDS (hi @0, lo @5120) ----
    {
        int e = ebase + lane;
        float x[32];
        x[0] = he_in[e];
        int sr = src[e], dd = dst[e];
        float4 a0 = *(const float4*)(h + sr * 8);
        float4 a1 = *(const float4*)(h + sr * 8 + 4);
        float4 d0 = *(const float4*)(h + dd * 8);
        float4 d1 = *(const float4*)(h + dd * 8 + 4);
        x[1] = a0.x;  x[2] = a0.y;  x[3] = a0.z;  x[4] = a0.w;
        x[5] = a1.x;  x[6] = a1.y;  x[7] = a1.z;  x[8] = a1.w;
        x[9] = d0.x;  x[10] = d0.y; x[11] = d0.z; x[12] = d0.w;
        x[13] = d1.x; x[14] = d1.y; x[15] = d1.z; x[16] = d1.w;
#pragma unroll
        for (int j = 17; j < 32; ++j) x[j] = 0.f;
        unsigned uh[16], ul[16];
#pragma unroll
        for (int jj = 0; jj < 16; ++jj) {
            unsigned short h0 = f2bf(x[2 * jj]);
            unsigned short h1v = f2bf(x[2 * jj + 1]);
            unsigned short l0 = f2bf(x[2 * jj] - bf2f(h0));
            unsigned short l1 = f2bf(x[2 * jj + 1] - bf2f(h1v));
            uh[jj] = (unsigned)h0 | ((unsigned)h1v << 16);
            ul[jj] = (unsigned)l0 | ((unsigned)l1 << 16);
        }
        uint4* ph = (uint4*)(W + lane * 80);
        uint4* pl = (uint4*)(W + 5120 + lane * 80);
#pragma unroll
        for (int q = 0; q < 4; ++q) {
            ph[q] = make_uint4(uh[4 * q], uh[4 * q + 1], uh[4 * q + 2], uh[4 * q + 3]);
            pl[q] = make_uint4(ul[4 * q], ul[4 * q + 1], ul[4 * q + 2], ul[4 * q + 3]);
        }
    }
    __syncthreads();
    const int row = lane & 15, g = lane >> 4;

    // ---- layer 1: D1[ch][edge] ----
    bf16x8 wa_h[4], wa_l[4];
#pragma unroll
    for (int mt = 0; mt < 4; ++mt) {
        wa_h[mt] = *(const bf16x8*)(w1hi + (16 * mt + row) * 32 + g * 8);
        wa_l[mt] = *(const bf16x8*)(w1lo + (16 * mt + row) * 32 + g * 8);
    }
    bf16x8 xb_h[4], xb_l[4];
#pragma unroll
    for (int nt = 0; nt < 4; ++nt) {
        xb_h[nt] = *(const bf16x8*)(W + (16 * nt + row) * 80 + g * 16);
        xb_l[nt] = *(const bf16x8*)(W + 5120 + (16 * nt + row) * 80 + g * 16);
    }
    f32x4 c1[4][4];
#pragma unroll
    for (int mt = 0; mt < 4; ++mt)
#pragma unroll
        for (int nt = 0; nt < 4; ++nt) {
            f32x4 c = {0.f, 0.f, 0.f, 0.f};
            c = __builtin_amdgcn_mfma_f32_16x16x32_bf16(wa_h[mt], xb_h[nt], c, 0, 0, 0);
            c = __builtin_amdgcn_mfma_f32_16x16x32_bf16(wa_h[mt], xb_l[nt], c, 0, 0, 0);
            c = __builtin_amdgcn_mfma_f32_16x16x32_bf16(wa_l[mt], xb_h[nt], c, 0, 0, 0);
            c1[mt][nt] = c;
        }

    // ---- bias+relu+split IN REGISTERS -> layer-2 B fragments (kappa') ----
    float4 b1v[4];
#pragma unroll
    for (int mt = 0; mt < 4; ++mt) b1v[mt] = *(const float4*)(b1 + 16 * mt + g * 4);
    bf16x8 pb_h[4][2], pb_l[4][2];
#pragma unroll
    for (int nt = 0; nt < 4; ++nt)
#pragma unroll
        for (int ks = 0; ks < 2; ++ks) {
            float v0 = fmaxf(c1[2 * ks][nt].x + b1v[2 * ks].x, 0.f);
            float v1 = fmaxf(c1[2 * ks][nt].y + b1v[2 * ks].y, 0.f);
            float v2 = fmaxf(c1[2 * ks][nt].z + b1v[2 * ks].z, 0.f);
            float v3 = fmaxf(c1[2 * ks][nt].w + b1v[2 * ks].w, 0.f);
            float v4 = fmaxf(c1[2 * ks + 1][nt].x + b1v[2 * ks + 1].x, 0.f);
            float v5 = fmaxf(c1[2 * ks + 1][nt].y + b1v[2 * ks + 1].y, 0.f);
            float v6 = fmaxf(c1[2 * ks + 1][nt].z + b1v[2 * ks + 1].z, 0.f);
            float v7 = fmaxf(c1[2 * ks + 1][nt].w + b1v[2 * ks + 1].w, 0.f);
            unsigned short h0 = f2bf(v0), h1v = f2bf(v1), h2v = f2bf(v2), h3 = f2bf(v3);
            unsigned short h4 = f2bf(v4), h5 = f2bf(v5), h6 = f2bf(v6), h7 = f2bf(v7);
            bf16x8 ph, pl;
            ph[0] = h0; ph[1] = h1v; ph[2] = h2v; ph[3] = h3;
            ph[4] = h4; ph[5] = h5;  ph[6] = h6;  ph[7] = h7;
            pl[0] = f2bf(v0 - bf2f(h0)); pl[1] = f2bf(v1 - bf2f(h1v));
            pl[2] = f2bf(v2 - bf2f(h2v)); pl[3] = f2bf(v3 - bf2f(h3));
            pl[4] = f2bf(v4 - bf2f(h4)); pl[5] = f2bf(v5 - bf2f(h5));
            pl[6] = f2bf(v6 - bf2f(h6)); pl[7] = f2bf(v7 - bf2f(h7));
            pb_h[nt][ks] = ph;
            pb_l[nt][ks] = pl;
        }

    // ---- layer 2: D2[outch][edge], A = w2 (kappa'-packed), B = pb ----
    f32x4 c2[4][4];
#pragma unroll
    for (int mt = 0; mt < 4; ++mt)
#pragma unroll
        for (int nt = 0; nt < 4; ++nt) c2[mt][nt] = (f32x4){0.f, 0.f, 0.f, 0.f};
#pragma unroll
    for (int mt = 0; mt < 4; ++mt) {
        bf16x8 w2a_h[2], w2a_l[2];
#pragma unroll
        for (int ks = 0; ks < 2; ++ks) {
            int off = (((mt * 2 + ks) * 16 + row) * 4 + g) * 8;
            w2a_h[ks] = *(const bf16x8*)(w2hi + off);
            w2a_l[ks] = *(const bf16x8*)(w2lo + off);
        }
#pragma unroll
        for (int nt = 0; nt < 4; ++nt)
#pragma unroll
            for (int ks = 0; ks < 2; ++ks) {
                c2[mt][nt] = __builtin_amdgcn_mfma_f32_16x16x32_bf16(w2a_h[ks], pb_h[nt][ks], c2[mt][nt], 0, 0, 0);
                c2[mt][nt] = __builtin_amdgcn_mfma_f32_16x16x32_bf16(w2a_h[ks], pb_l[nt][ks], c2[mt][nt], 0, 0, 0);
                c2[mt][nt] = __builtin_amdgcn_mfma_f32_16x16x32_bf16(w2a_l[ks], pb_h[nt][ks], c2[mt][nt], 0, 0, 0);
            }
    }

    // ---- layer 3 epilogue: out = relu(b3 + sum_ch relu(h2)*w3) ----
    float4 b2v[4], w3v[4];
#pragma unroll
    for (int mt = 0; mt < 4; ++mt) {
        b2v[mt] = *(const float4*)(b2 + 16 * mt + g * 4);
        w3v[mt] = *(const float4*)(w3 + 16 * mt + g * 4);
    }
    float b3s = b3[0];
    float pacc[4];
#pragma unroll
    for (int nt = 0; nt < 4; ++nt) {
        float p = 0.f;
#pragma unroll
        for (int mt = 0; mt < 4; ++mt) {
            p = fmaf(fmaxf(c2[mt][nt].x + b2v[mt].x, 0.f), w3v[mt].x, p);
            p = fmaf(fmaxf(c2[mt][nt].y + b2v[mt].y, 0.f), w3v[mt].y, p);
            p = fmaf(fmaxf(c2[mt][nt].z + b2v[mt].z, 0.f), w3v[mt].z, p);
            p = fmaf(fmaxf(c2[mt][nt].w + b2v[mt].w, 0.f), w3v[mt].w, p);
        }
        p += __shfl_xor(p, 16);
        p += __shfl_xor(p, 32);
        pacc[nt] = p;
    }
    if (lane < 16) {
#pragma unroll
        for (int nt = 0; nt < 4; ++nt) {
            int e2 = ebase + 16 * nt + lane;
            float o = fmaxf(pacc[nt] + b3s, 0.f);
            he_out[e2] = o;
            atomicAdd(agg + dst[e2], o);
        }
    }
}

extern "C" void kernel_launch(void* const* d_in, const int* in_sizes, int n_in,
                              void* d_out, int out_size, void* d_ws, size_t ws_size,
                              hipStream_t stream) {
    const int N = N_NODES, E = N_EDGES;
    const float* node_feat = (const float*)d_in[0];
    const float* edge_feat = (const float*)d_in[1];
    const float* edge_dist = (const float*)d_in[2];
    const int* src = (const int*)d_in[3];
    const int* dst = (const int*)d_in[4];
    const float* w_enc1 = (const float*)d_in[5];  const float* b_enc1 = (const float*)d_in[6];
    const float* w_enc2 = (const float*)d_in[7];  const float* b_enc2 = (const float*)d_in[8];
    const float* w_enc3 = (const float*)d_in[9];  const float* b_enc3 = (const float*)d_in[10];
    const float* w_dec1 = (const float*)d_in[11]; const float* b_dec1 = (const float*)d_in[12];
    const float* w_dec2 = (const float*)d_in[13]; const float* b_dec2 = (const float*)d_in[14];
    const float* w_dec3 = (const float*)d_in[15]; const float* b_dec3 = (const float*)d_in[16];
    const float* w_nod1 = (const float*)d_in[17]; const float* b_nod1 = (const float*)d_in[18];
    const float* w_nod2 = (const float*)d_in[19]; const float* b_nod2 = (const float*)d_in[20];
    const float* w_nod3 = (const float*)d_in[21]; const float* b_nod3 = (const float*)d_in[22];
    const float* w_edg1 = (const float*)d_in[23]; const float* b_edg1 = (const float*)d_in[24];
    const float* w_edg2 = (const float*)d_in[25]; const float* b_edg2 = (const float*)d_in[26];
    const float* w_edg3 = (const float*)d_in[27]; const float* b_edg3 = (const float*)d_in[28];

    float* ws = (float*)d_ws;
    float* s      = ws;            // N
    float* hagg1  = ws + N;        // 8N
    float* agg1   = ws + 9 * N;    // N
    float* agg2   = ws + 10 * N;   // N
    float* hagg2  = ws + 11 * N;   // 8N   (zero range = 19N)
    float* rs     = ws + 19 * N;   // N (fully written by norm_kernel)
    float* h_enc  = ws + 20 * N;
    float* h_r1   = ws + 28 * N;
    float* h_r2   = ws + 36 * N;
    float* wbuf   = ws + 44 * N;
    float* he1    = wbuf + E;
    float* he2    = he1 + E;
    float* pk_enc = he2 + E;            // 64*80
    float* pk_nod = pk_enc + 64 * 80;   // 64*80
    float* pk_dec = pk_nod + 64 * 80;   // 64*80
    unsigned short* w1hi = (unsigned short*)(pk_dec + 64 * 80);
    unsigned short* w1lo = w1hi + 64 * 32;
    unsigned short* w2hi = w1lo + 64 * 32;
    unsigned short* w2lo = w2hi + 64 * 64;

    // pack weights (runs every call; inputs restored by harness)
    PackArgs pa0{w_enc1, b_enc1, w_enc2, pk_enc, 3, 80};
    PackArgs pa1{w_nod1, b_nod1, w_nod2, pk_nod, 9, 80};
    PackArgs pa2{w_dec1, b_dec1, w_dec2, pk_dec, 8, 80};
    pack_kernel<<<3, 64, 0, stream>>>(pa0, pa1, pa2);
    pack_edge_kernel<<<1, 64, 0, stream>>>(w_edg1, w_edg2, w1hi, w1lo, w2hi, w2lo);

    // zero accumulators (s, hagg1, agg1, agg2, hagg2)
    zero_kernel<<<2048, 256, 0, stream>>>(ws, 19 * N);
    // encoder
    node_mlp_kernel<3, 0, 8, 80><<<(N + 255) / 256, 256, 0, stream>>>(node_feat, nullptr,
        nullptr, pk_enc, b_enc2, w_enc3, b_enc3, h_enc, N);
    // fused softmax-numerator + first aggregation (E*8 coalesced scatter)
    exp_agg_kernel<<<(E * 8 + 255) / 256, 256, 0, stream>>>(edge_dist, src, dst, h_enc,
        s, wbuf, hagg1, E);
    // normalize hagg1 by s; cache rs = 1/s for decoder
    norm_kernel<<<(N + 255) / 256, 256, 0, stream>>>(hagg1, s, rs, N);
    // round 1  (E = 128*12500 exactly)
    edge_mlp_mfma_kernel<<<E / 128, 128, 0, stream>>>(edge_feat, hagg1, src, dst,
        w1hi, w1lo, w2hi, w2lo, b_edg1, b_edg2, w_edg3, b_edg3, he1, agg1);
    node_mlp_kernel<1, 8, 8, 80><<<(N + 255) / 256, 256, 0, stream>>>(agg1, hagg1,
        nullptr, pk_nod, b_nod2, w_nod3, b_nod3, h_r1, N);
    // round 2
    edge_mlp_mfma_kernel<<<E / 128, 128, 0, stream>>>(he1, h_r1, src, dst,
        w1hi, w1lo, w2hi, w2lo, b_edg1, b_edg2, w_edg3, b_edg3, he2, agg2);
    node_mlp_kernel<1, 8, 8, 80><<<(N + 255) / 256, 256, 0, stream>>>(agg2, h_r1,
        nullptr, pk_nod, b_nod2, w_nod3, b_nod3, h_r2, N);
    // second weighted aggregation (raw exp; decoder divides by s via rs)
    agg2_kernel<<<(E * 8 + 255) / 256, 256, 0, stream>>>(wbuf, h_r2, src, dst, hagg2, E);
    // decoder -> output (x = hagg2 * rs)
    node_mlp_kernel<8, 0, 1, 80><<<(N + 255) / 256, 256, 0, stream>>>(hagg2, nullptr,
        rs, pk_dec, b_dec2, w_dec3, b_dec3, (float*)d_out, N);
}